// Round 3
// baseline (239.983 us; speedup 1.0000x reference)
//
#include <hip/hip_runtime.h>
#include <hip/hip_bf16.h>
#include <stdint.h>

typedef __attribute__((ext_vector_type(8))) __bf16 bf16x8;
typedef __attribute__((ext_vector_type(4))) float f32x4;
typedef __attribute__((ext_vector_type(4))) unsigned int u32x4;

#define SEQ 1024
#define DM 1024

typedef __attribute__((address_space(3))) void lds_t;
typedef __attribute__((address_space(1))) void glb_t;

__device__ __forceinline__ unsigned short f2bf(float f){
  __hip_bfloat16 h = __float2bfloat16(f);
  return __builtin_bit_cast(unsigned short, h);
}
__device__ __forceinline__ bf16x8 ld16(const unsigned short* p){
  u32x4 v = *(const u32x4*)p;
  return __builtin_bit_cast(bf16x8, v);
}
__device__ __forceinline__ void gload_lds16(const unsigned short* g, unsigned short* l){
  __builtin_amdgcn_global_load_lds((const glb_t*)g, (lds_t*)l, 16, 0, 0);
}

// ---------------- fp32 -> bf16 convert (x activations) ----------------------
__global__ void cvt_f32_bf16(const float* __restrict__ in,
                             unsigned short* __restrict__ out, int n)
{
  int i = (blockIdx.x * blockDim.x + threadIdx.x) * 8;
  if (i >= n) return;
  float4 a = *(const float4*)(in + i);
  float4 b = *(const float4*)(in + i + 4);
  unsigned short v[8] = { f2bf(a.x), f2bf(a.y), f2bf(a.z), f2bf(a.w),
                          f2bf(b.x), f2bf(b.y), f2bf(b.z), f2bf(b.w) };
  *(u32x4*)(out + i) = *(u32x4*)v;
}

// -------- fp32 weights: [R][C] -> bf16 [C][R] (convert + transpose) ---------
__global__ void transpose_cvt(const float* __restrict__ in,
                              unsigned short* __restrict__ out, int R, int C)
{
  __shared__ unsigned short t[32][33];
  int x  = blockIdx.x * 32 + threadIdx.x;
  int y0 = blockIdx.y * 32 + threadIdx.y;
#pragma unroll
  for (int i = 0; i < 32; i += 8)
    t[threadIdx.y + i][threadIdx.x] = f2bf(in[(size_t)(y0 + i) * C + x]);
  __syncthreads();
  int ox  = blockIdx.y * 32 + threadIdx.x;   // original row
  int oy0 = blockIdx.x * 32 + threadIdx.y;   // original col
#pragma unroll
  for (int i = 0; i < 32; i += 8)
    out[(size_t)(oy0 + i) * R + ox] = t[threadIdx.x][threadIdx.y + i];
}

// ---------------- bf16 GEMM: C[M][N] = A[M][K] * Bt[N][K]^T + bias ----------
// 128x128 tile, BK=32, 256 threads (2x2 waves of 64x64), m97 structure.
// OUT_F32: store fp32 (final output) vs bf16 (internal).
template <bool OUT_F32>
__global__ __launch_bounds__(256, 2)
void gemm_bt(const unsigned short* __restrict__ A,
             const unsigned short* __restrict__ Bt,
             const float* __restrict__ bias,
             void* __restrict__ Cout,
             int M, int N, int K, int scaleQ)
{
  __shared__ unsigned short As[128 * 32];
  __shared__ unsigned short Bs[128 * 32];
  const int tid = threadIdx.x;
  const int l = tid & 63;
  const int w = tid >> 6;

  const int nbn = N >> 7;
  const int nwg = gridDim.x;
  const int bid = blockIdx.x;
  const int qq  = nwg >> 3;                       // grid % 8 == 0 guaranteed
  const int sb  = (bid & 7) * qq + (bid >> 3);    // XCD-bijective swizzle
  const int bm = sb / nbn, bn = sb % nbn;
  const int row0 = bm << 7, col0 = bn << 7;

  // staging coords: inst i covers rows i*64 + w*16 + (l>>2), 16B chunk (l&3)
  const int rA = w * 16 + (l >> 2);
  const int cA = (l & 3) * 8;
  const unsigned short* ag = A  + (size_t)(row0 + rA) * K + cA;
  const unsigned short* bg = Bt + (size_t)(col0 + rA) * K + cA;
  unsigned short* la0 = As + w * 512;
  unsigned short* lb0 = Bs + w * 512;

  const int wr = (w >> 1) * 64, wc = (w & 1) * 64;
  const f32x4 zz = {0.f, 0.f, 0.f, 0.f};
  f32x4 acc[4][4];
#pragma unroll
  for (int m = 0; m < 4; m++)
#pragma unroll
    for (int n = 0; n < 4; n++) acc[m][n] = zz;

  for (int k0 = 0; k0 < K; k0 += 32) {
    __syncthreads();
    gload_lds16(ag + k0,                  la0);
    gload_lds16(ag + k0 + (size_t)64 * K, la0 + 2048);
    gload_lds16(bg + k0,                  lb0);
    gload_lds16(bg + k0 + (size_t)64 * K, lb0 + 2048);
    __syncthreads();
    bf16x8 af[4], bfr[4];
#pragma unroll
    for (int m = 0; m < 4; m++)
      af[m] = ld16(As + (wr + m * 16 + (l & 15)) * 32 + (l >> 4) * 8);
#pragma unroll
    for (int n = 0; n < 4; n++)
      bfr[n] = ld16(Bs + (wc + n * 16 + (l & 15)) * 32 + (l >> 4) * 8);
#pragma unroll
    for (int m = 0; m < 4; m++)
#pragma unroll
      for (int n = 0; n < 4; n++)
        acc[m][n] = __builtin_amdgcn_mfma_f32_16x16x32_bf16(af[m], bfr[n], acc[m][n], 0, 0, 0);
  }

  // epilogue: +bias (fp32), optional Q scale (cols < DM), store
#pragma unroll
  for (int n = 0; n < 4; n++) {
    int col = col0 + wc + n * 16 + (l & 15);
    float bv = bias[col];
    float scale = (scaleQ && col < DM) ? 0.125f : 1.0f;
#pragma unroll
    for (int m = 0; m < 4; m++) {
      int rbase = row0 + wr + m * 16 + (l >> 4) * 4;
#pragma unroll
      for (int r = 0; r < 4; r++) {
        float v = (acc[m][n][r] + bv) * scale;
        if (OUT_F32)
          ((float*)Cout)[(size_t)(rbase + r) * N + col] = v;
        else
          ((unsigned short*)Cout)[(size_t)(rbase + r) * N + col] = f2bf(v);
      }
    }
  }
}

// ---------------- causal flash attention --------------------------------
// qkv: [b][s][3*DM] bf16 (Q pre-scaled by 0.125). ctx: [b][s][DM] bf16.
// grid: (8 q-tiles, 128 b*h). 256 thr = 4 waves, each wave 32 q-rows.
__global__ __launch_bounds__(256, 2)
void attn(const unsigned short* __restrict__ qkv, unsigned short* __restrict__ ctx)
{
  __shared__ unsigned short Ks[64 * 64];   // [kv][d], XOR-swizzled
  __shared__ unsigned short Vt[64 * 64];   // [d][kv], XOR-swizzled
  __shared__ unsigned short Ps[128 * 64];  // [q_local][kv], per-wave slabs
  const int tid = threadIdx.x;
  const int l = tid & 63, w = tid >> 6;
  const int qb = blockIdx.x;
  const int bh = blockIdx.y;
  const int b = bh >> 4, h = bh & 15;
  const unsigned short* base = qkv + (size_t)b * SEQ * 3072;
  const int q0 = qb * 128 + w * 32;

  // Q fragments (A-operand): rows q0+m*16+(l&15), k=d=kg*32+(l>>4)*8
  bf16x8 qa[2][2];
#pragma unroll
  for (int m = 0; m < 2; m++)
#pragma unroll
    for (int kg = 0; kg < 2; kg++)
      qa[m][kg] = ld16(base + (size_t)(q0 + m * 16 + (l & 15)) * 3072
                            + h * 64 + kg * 32 + (l >> 4) * 8);

  const f32x4 zz = {0.f, 0.f, 0.f, 0.f};
  f32x4 o[2][4];
#pragma unroll
  for (int m = 0; m < 2; m++)
#pragma unroll
    for (int n = 0; n < 4; n++) o[m][n] = zz;
  float mrun[2][4], lrun[2][4];
#pragma unroll
  for (int m = 0; m < 2; m++)
#pragma unroll
    for (int r = 0; r < 4; r++) { mrun[m][r] = -1e30f; lrun[m][r] = 0.f; }

  const int kvr = w * 8 + (l >> 3);
  const int cb  = (l & 7) * 16;
  const int nt = (qb + 1) * 2;

  for (int kvt = 0; kvt < nt; kvt++) {
    __syncthreads();
    // stage K tile: LDS linear, global source pre-swizzled (involution)
#pragma unroll
    for (int i = 0; i < 2; i++) {
      int row = i * 32 + kvr;
      int srcb = cb ^ ((row & 7) << 4);
      gload_lds16(base + (size_t)(kvt * 64 + row) * 3072 + DM + h * 64 + (srcb >> 1),
                  Ks + i * 2048 + w * 512);
    }
    // stage V transposed: reg load (coalesced) -> scalar ds writes, swizzled
#pragma unroll
    for (int i = 0; i < 2; i++) {
      int row = i * 32 + kvr;              // kv index
      int d0 = (l & 7) * 8;
      u32x4 vv = *(const u32x4*)(base + (size_t)(kvt * 64 + row) * 3072
                                      + 2 * DM + h * 64 + d0);
      unsigned short* vs = (unsigned short*)&vv;
#pragma unroll
      for (int j = 0; j < 8; j++) {
        int d = d0 + j;
        int byteoff = (row * 2) ^ ((d & 7) << 4);
        Vt[d * 64 + (byteoff >> 1)] = vs[j];
      }
    }
    __syncthreads();

    if (kvt * 64 <= q0 + 31) {   // skip tiles fully above this wave's diagonal
      // S = Q K^T
      f32x4 s[2][4];
#pragma unroll
      for (int m = 0; m < 2; m++)
#pragma unroll
        for (int n = 0; n < 4; n++) s[m][n] = zz;
#pragma unroll
      for (int kg = 0; kg < 2; kg++) {
        bf16x8 kb[4];
#pragma unroll
        for (int n = 0; n < 4; n++) {
          int kvc = n * 16 + (l & 15);
          int byteoff = ((kg * 32 + (l >> 4) * 8) * 2) ^ ((kvc & 7) << 4);
          kb[n] = ld16(Ks + kvc * 64 + (byteoff >> 1));
        }
#pragma unroll
        for (int m = 0; m < 2; m++)
#pragma unroll
          for (int n = 0; n < 4; n++)
            s[m][n] = __builtin_amdgcn_mfma_f32_16x16x32_bf16(qa[m][kg], kb[n], s[m][n], 0, 0, 0);
      }
      // causal mask
      if (kvt * 64 + 63 > q0) {
#pragma unroll
        for (int m = 0; m < 2; m++)
#pragma unroll
          for (int r = 0; r < 4; r++) {
            int qg = q0 + m * 16 + (l >> 4) * 4 + r;
#pragma unroll
            for (int n = 0; n < 4; n++) {
              int kvg = kvt * 64 + n * 16 + (l & 15);
              if (kvg > qg) s[m][n][r] = -1e30f;
            }
          }
      }
      // online softmax (16-lane shuffle reduce; rows live in lane-groups)
#pragma unroll
      for (int m = 0; m < 2; m++)
#pragma unroll
        for (int r = 0; r < 4; r++) {
          float mx = fmaxf(fmaxf(s[m][0][r], s[m][1][r]), fmaxf(s[m][2][r], s[m][3][r]));
          mx = fmaxf(mx, __shfl_xor(mx, 1));
          mx = fmaxf(mx, __shfl_xor(mx, 2));
          mx = fmaxf(mx, __shfl_xor(mx, 4));
          mx = fmaxf(mx, __shfl_xor(mx, 8));
          float mn = fmaxf(mrun[m][r], mx);
          float sc = __expf(mrun[m][r] - mn);
          mrun[m][r] = mn;
          float rs = 0.f;
#pragma unroll
          for (int n = 0; n < 4; n++) {
            float p = __expf(s[m][n][r] - mn);
            s[m][n][r] = p;
            rs += p;
          }
          rs += __shfl_xor(rs, 1); rs += __shfl_xor(rs, 2);
          rs += __shfl_xor(rs, 4); rs += __shfl_xor(rs, 8);
          lrun[m][r] = lrun[m][r] * sc + rs;
#pragma unroll
          for (int n = 0; n < 4; n++) o[m][n][r] *= sc;
        }
      // P -> LDS (bf16, swizzled). Per-wave slab: no barrier needed.
#pragma unroll
      for (int m = 0; m < 2; m++)
#pragma unroll
        for (int n = 0; n < 4; n++)
#pragma unroll
          for (int r = 0; r < 4; r++) {
            int rowl = w * 32 + m * 16 + (l >> 4) * 4 + r;
            int byteoff = ((n * 16 + (l & 15)) * 2) ^ ((rowl & 7) << 4);
            Ps[rowl * 64 + (byteoff >> 1)] = f2bf(s[m][n][r]);
          }
      // O += P V
#pragma unroll
      for (int kg = 0; kg < 2; kg++) {
        bf16x8 pa[2], vb[4];
#pragma unroll
        for (int m = 0; m < 2; m++) {
          int rowl = w * 32 + m * 16 + (l & 15);
          int byteoff = ((kg * 32 + (l >> 4) * 8) * 2) ^ ((rowl & 7) << 4);
          pa[m] = ld16(Ps + rowl * 64 + (byteoff >> 1));
        }
#pragma unroll
        for (int n = 0; n < 4; n++) {
          int d = n * 16 + (l & 15);
          int byteoff = ((kg * 32 + (l >> 4) * 8) * 2) ^ ((d & 7) << 4);
          vb[n] = ld16(Vt + d * 64 + (byteoff >> 1));
        }
#pragma unroll
        for (int m = 0; m < 2; m++)
#pragma unroll
          for (int n = 0; n < 4; n++)
            o[m][n] = __builtin_amdgcn_mfma_f32_16x16x32_bf16(pa[m], vb[n], o[m][n], 0, 0, 0);
      }
    }
  }

  // write context [b][s][h*64+d]
#pragma unroll
  for (int m = 0; m < 2; m++)
#pragma unroll
    for (int r = 0; r < 4; r++) {
      float inv = 1.f / lrun[m][r];
      int qg = q0 + m * 16 + (l >> 4) * 4 + r;
#pragma unroll
      for (int n = 0; n < 4; n++) {
        int d = n * 16 + (l & 15);
        ctx[(size_t)(b * SEQ + qg) * DM + h * 64 + d] = f2bf(o[m][n][r] * inv);
      }
    }
}

extern "C" void kernel_launch(void* const* d_in, const int* in_sizes, int n_in,
                              void* d_out, int out_size, void* d_ws, size_t ws_size,
                              hipStream_t stream)
{
  const float* x     = (const float*)d_in[0];
  const float* qkv_w = (const float*)d_in[1];
  const float* qkv_b = (const float*)d_in[2];
  const float* out_w = (const float*)d_in[3];
  const float* out_b = (const float*)d_in[4];

  unsigned short* ws   = (unsigned short*)d_ws;
  unsigned short* xb   = ws;                          // 8192*1024
  unsigned short* wqT  = xb  + (size_t)8192 * 1024;   // 3072*1024
  unsigned short* woT  = wqT + 3072 * 1024;           // 1024*1024
  unsigned short* qkvb = woT + 1024 * 1024;           // 8192*3072
  unsigned short* ctxb = qkvb + (size_t)8192 * 3072;  // 8192*1024  (total ~92 MB)

  hipLaunchKernelGGL(cvt_f32_bf16, dim3(8192 * 1024 / 8 / 256), dim3(256), 0, stream,
                     x, xb, 8192 * 1024);
  hipLaunchKernelGGL(transpose_cvt, dim3(3072 / 32, 1024 / 32), dim3(32, 8), 0, stream,
                     qkv_w, wqT, 1024, 3072);
  hipLaunchKernelGGL(transpose_cvt, dim3(1024 / 32, 1024 / 32), dim3(32, 8), 0, stream,
                     out_w, woT, 1024, 1024);
  hipLaunchKernelGGL(gemm_bt<false>, dim3(64 * 24), dim3(256), 0, stream,
                     xb, wqT, qkv_b, (void*)qkvb, 8192, 3072, 1024, 1);
  hipLaunchKernelGGL(attn, dim3(8, 128), dim3(256), 0, stream,
                     qkvb, ctxb);
  hipLaunchKernelGGL(gemm_bt<true>, dim3(64 * 8), dim3(256), 0, stream,
                     ctxb, woT, out_b, d_out, 8192, 1024, 1024, 0);
}

// Round 4
// 221.319 us; speedup vs baseline: 1.0843x; 1.0843x over previous
//
#include <hip/hip_runtime.h>
#include <hip/hip_bf16.h>
#include <stdint.h>

typedef __attribute__((ext_vector_type(8))) __bf16 bf16x8;
typedef __attribute__((ext_vector_type(4))) float f32x4;
typedef __attribute__((ext_vector_type(4))) unsigned int u32x4;
typedef __attribute__((ext_vector_type(4))) unsigned short u16x4;

#define SEQ 1024
#define DM 1024

typedef __attribute__((address_space(3))) void lds_t;
typedef __attribute__((address_space(1))) void glb_t;

__device__ __forceinline__ unsigned short f2bf(float f){
  __hip_bfloat16 h = __float2bfloat16(f);
  return __builtin_bit_cast(unsigned short, h);
}
__device__ __forceinline__ bf16x8 ld16(const unsigned short* p){
  u32x4 v = *(const u32x4*)p;
  return __builtin_bit_cast(bf16x8, v);
}
__device__ __forceinline__ void gload_lds16(const unsigned short* g, unsigned short* l){
  __builtin_amdgcn_global_load_lds((const glb_t*)g, (lds_t*)l, 16, 0, 0);
}

// ---------------- fp32 -> bf16 convert (x activations) ----------------------
__global__ void cvt_f32_bf16(const float* __restrict__ in,
                             unsigned short* __restrict__ out, int n)
{
  int i = (blockIdx.x * blockDim.x + threadIdx.x) * 8;
  if (i >= n) return;
  float4 a = *(const float4*)(in + i);
  float4 b = *(const float4*)(in + i + 4);
  unsigned short v[8] = { f2bf(a.x), f2bf(a.y), f2bf(a.z), f2bf(a.w),
                          f2bf(b.x), f2bf(b.y), f2bf(b.z), f2bf(b.w) };
  *(u32x4*)(out + i) = *(u32x4*)v;
}

// -------- fp32 weights: [R][C] -> bf16 [C][R] (convert + transpose) ---------
__global__ void transpose_cvt(const float* __restrict__ in,
                              unsigned short* __restrict__ out, int R, int C)
{
  __shared__ unsigned short t[32][33];
  int x  = blockIdx.x * 32 + threadIdx.x;
  int y0 = blockIdx.y * 32 + threadIdx.y;
#pragma unroll
  for (int i = 0; i < 32; i += 8)
    t[threadIdx.y + i][threadIdx.x] = f2bf(in[(size_t)(y0 + i) * C + x]);
  __syncthreads();
  int ox  = blockIdx.y * 32 + threadIdx.x;   // original row
  int oy0 = blockIdx.x * 32 + threadIdx.y;   // original col
#pragma unroll
  for (int i = 0; i < 32; i += 8)
    out[(size_t)(oy0 + i) * R + ox] = t[threadIdx.x][threadIdx.y + i];
}

// ---------------- bf16 GEMM: C = A[M][K] * Bt[N][K]^T + bias ----------------
// 128x128 tile, BK=32, 256 threads (2x2 waves of 64x64), m97 structure.
// MODE 1: QKV split epilogue -> qk[b][s][2048] (Q scaled 0.125) + vT[b][h][d][s]
// MODE 2: fp32 store to C0[M][N]
template <int MODE>
__global__ __launch_bounds__(256, 2)
void gemm_bt(const unsigned short* __restrict__ A,
             const unsigned short* __restrict__ Bt,
             const float* __restrict__ bias,
             void* __restrict__ C0, unsigned short* __restrict__ vT,
             int M, int N, int K)
{
  __shared__ unsigned short As[128 * 32];
  __shared__ unsigned short Bs[128 * 32];
  const int tid = threadIdx.x;
  const int l = tid & 63;
  const int w = tid >> 6;

  const int nbn = N >> 7;
  const int nwg = gridDim.x;
  const int bid = blockIdx.x;
  const int qq  = nwg >> 3;                       // grid % 8 == 0 guaranteed
  const int sb  = (bid & 7) * qq + (bid >> 3);    // XCD-bijective swizzle
  const int bm = sb / nbn, bn = sb % nbn;
  const int row0 = bm << 7, col0 = bn << 7;

  const int rA = w * 16 + (l >> 2);
  const int cA = (l & 3) * 8;
  const unsigned short* ag = A  + (size_t)(row0 + rA) * K + cA;
  const unsigned short* bg = Bt + (size_t)(col0 + rA) * K + cA;
  unsigned short* la0 = As + w * 512;
  unsigned short* lb0 = Bs + w * 512;

  const int wr = (w >> 1) * 64, wc = (w & 1) * 64;
  const f32x4 zz = {0.f, 0.f, 0.f, 0.f};
  f32x4 acc[4][4];
#pragma unroll
  for (int m = 0; m < 4; m++)
#pragma unroll
    for (int n = 0; n < 4; n++) acc[m][n] = zz;

  for (int k0 = 0; k0 < K; k0 += 32) {
    __syncthreads();
    gload_lds16(ag + k0,                  la0);
    gload_lds16(ag + k0 + (size_t)64 * K, la0 + 2048);
    gload_lds16(bg + k0,                  lb0);
    gload_lds16(bg + k0 + (size_t)64 * K, lb0 + 2048);
    __syncthreads();
    bf16x8 af[4], bfr[4];
#pragma unroll
    for (int m = 0; m < 4; m++)
      af[m] = ld16(As + (wr + m * 16 + (l & 15)) * 32 + (l >> 4) * 8);
#pragma unroll
    for (int n = 0; n < 4; n++)
      bfr[n] = ld16(Bs + (wc + n * 16 + (l & 15)) * 32 + (l >> 4) * 8);
#pragma unroll
    for (int m = 0; m < 4; m++)
#pragma unroll
      for (int n = 0; n < 4; n++)
        acc[m][n] = __builtin_amdgcn_mfma_f32_16x16x32_bf16(af[m], bfr[n], acc[m][n], 0, 0, 0);
  }

#pragma unroll
  for (int n = 0; n < 4; n++) {
    int col = col0 + wc + n * 16 + (l & 15);
    float bv = bias[col];
#pragma unroll
    for (int m = 0; m < 4; m++) {
      int rbase = row0 + wr + m * 16 + (l >> 4) * 4;
      if constexpr (MODE == 2) {
#pragma unroll
        for (int r = 0; r < 4; r++)
          ((float*)C0)[(size_t)(rbase + r) * N + col] = acc[m][n][r] + bv;
      } else {
        if (col < 2048) {   // Q or K -> qk buffer [b][s][2048]
          float sc = (col < 1024) ? 0.125f : 1.0f;
#pragma unroll
          for (int r = 0; r < 4; r++)
            ((unsigned short*)C0)[(size_t)(rbase + r) * 2048 + col] =
                f2bf((acc[m][n][r] + bv) * sc);
        } else {            // V -> vT[b][h][d][s], 8B packed along s
          int bb = rbase >> 10, s0 = rbase & 1023;
          int hh = (col - 2048) >> 6, dd = (col - 2048) & 63;
          u16x4 pk;
#pragma unroll
          for (int r = 0; r < 4; r++) pk[r] = f2bf(acc[m][n][r] + bv);
          *(u16x4*)(vT + ((size_t)((bb * 16 + hh) * 64 + dd)) * 1024 + s0) = pk;
        }
      }
    }
  }
}

// ---------------- causal flash attention --------------------------------
// qk: [b][s][2048] bf16 (Q scaled). vT: [b][h][d][s] bf16. ctx: [b][s][DM].
// grid (8, 128); 4 waves; 2-phase double-buffered K/V staging.
__global__ __launch_bounds__(256, 2)
void attn(const unsigned short* __restrict__ qk,
          const unsigned short* __restrict__ vT,
          unsigned short* __restrict__ ctx)
{
  __shared__ unsigned short Ksh[2][64 * 64];   // [kv][d], XOR-swizzled
  __shared__ unsigned short Vsh[2][64 * 64];   // [d][kv], XOR-swizzled
  __shared__ unsigned short Ps[128 * 64];      // per-wave P slabs
  const int tid = threadIdx.x;
  const int l = tid & 63, w = tid >> 6;
  const int qb = 7 - blockIdx.x;               // heavy blocks first
  const int bh = blockIdx.y;
  const int b = bh >> 4, h = bh & 15;
  const unsigned short* qbase = qk + (size_t)b * SEQ * 2048;
  const int q0 = qb * 128 + w * 32;

  bf16x8 qa[2][2];
#pragma unroll
  for (int m = 0; m < 2; m++)
#pragma unroll
    for (int kg = 0; kg < 2; kg++)
      qa[m][kg] = ld16(qbase + (size_t)(q0 + m * 16 + (l & 15)) * 2048
                             + h * 64 + kg * 32 + (l >> 4) * 8);

  const f32x4 zz = {0.f, 0.f, 0.f, 0.f};
  f32x4 o[2][4];
#pragma unroll
  for (int m = 0; m < 2; m++)
#pragma unroll
    for (int n = 0; n < 4; n++) o[m][n] = zz;
  float mrun[2][4], lrun[2][4];
#pragma unroll
  for (int m = 0; m < 2; m++)
#pragma unroll
    for (int r = 0; r < 4; r++) { mrun[m][r] = -1e30f; lrun[m][r] = 0.f; }

  const int kvr = w * 8 + (l >> 3);
  const int cb  = (l & 7) * 16;
  const int nt = (qb + 1) * 2;

  auto STAGE = [&](int t, int bufi) {
#pragma unroll
    for (int i = 0; i < 2; i++) {
      int row = i * 32 + kvr;
      int srcb = cb ^ ((row & 7) << 4);
      gload_lds16(qbase + (size_t)(t * 64 + row) * 2048 + 1024 + h * 64 + (srcb >> 1),
                  &Ksh[bufi][i * 2048 + w * 512]);
      gload_lds16(vT + ((size_t)(bh * 64 + row)) * 1024 + t * 64 + (srcb >> 1),
                  &Vsh[bufi][i * 2048 + w * 512]);
    }
  };

  STAGE(0, 0);
  asm volatile("s_waitcnt vmcnt(0)" ::: "memory");
  __builtin_amdgcn_s_barrier();

  int cur = 0;
  for (int kvt = 0; kvt < nt; kvt++) {
    if (kvt + 1 < nt) STAGE(kvt + 1, cur ^ 1);

    if (kvt * 64 <= q0 + 31) {
      const unsigned short* Kc = Ksh[cur];
      const unsigned short* Vc = Vsh[cur];
      // S = Q K^T
      f32x4 s[2][4];
#pragma unroll
      for (int m = 0; m < 2; m++)
#pragma unroll
        for (int n = 0; n < 4; n++) s[m][n] = zz;
#pragma unroll
      for (int kg = 0; kg < 2; kg++) {
        bf16x8 kb[4];
#pragma unroll
        for (int n = 0; n < 4; n++) {
          int kvc = n * 16 + (l & 15);
          int byteoff = ((kg * 32 + (l >> 4) * 8) * 2) ^ ((kvc & 7) << 4);
          kb[n] = ld16(Kc + kvc * 64 + (byteoff >> 1));
        }
#pragma unroll
        for (int m = 0; m < 2; m++)
#pragma unroll
          for (int n = 0; n < 4; n++)
            s[m][n] = __builtin_amdgcn_mfma_f32_16x16x32_bf16(qa[m][kg], kb[n], s[m][n], 0, 0, 0);
      }
      // causal mask (boundary tiles only)
      if (kvt * 64 + 63 > q0) {
#pragma unroll
        for (int m = 0; m < 2; m++)
#pragma unroll
          for (int r = 0; r < 4; r++) {
            int qg = q0 + m * 16 + (l >> 4) * 4 + r;
#pragma unroll
            for (int n = 0; n < 4; n++) {
              int kvg = kvt * 64 + n * 16 + (l & 15);
              if (kvg > qg) s[m][n][r] = -1e30f;
            }
          }
      }
      // online softmax (16-lane shuffle reduce)
#pragma unroll
      for (int m = 0; m < 2; m++)
#pragma unroll
        for (int r = 0; r < 4; r++) {
          float mx = fmaxf(fmaxf(s[m][0][r], s[m][1][r]), fmaxf(s[m][2][r], s[m][3][r]));
          mx = fmaxf(mx, __shfl_xor(mx, 1));
          mx = fmaxf(mx, __shfl_xor(mx, 2));
          mx = fmaxf(mx, __shfl_xor(mx, 4));
          mx = fmaxf(mx, __shfl_xor(mx, 8));
          float mn = fmaxf(mrun[m][r], mx);
          float sc = __expf(mrun[m][r] - mn);
          mrun[m][r] = mn;
          float rs = 0.f;
#pragma unroll
          for (int n = 0; n < 4; n++) {
            float p = __expf(s[m][n][r] - mn);
            s[m][n][r] = p;
            rs += p;
          }
          rs += __shfl_xor(rs, 1); rs += __shfl_xor(rs, 2);
          rs += __shfl_xor(rs, 4); rs += __shfl_xor(rs, 8);
          lrun[m][r] = lrun[m][r] * sc + rs;
#pragma unroll
          for (int n = 0; n < 4; n++) o[m][n][r] *= sc;
        }
      // P -> LDS (bf16, swizzled). Per-wave slab: no barrier needed.
#pragma unroll
      for (int m = 0; m < 2; m++)
#pragma unroll
        for (int n = 0; n < 4; n++)
#pragma unroll
          for (int r = 0; r < 4; r++) {
            int rowl = w * 32 + m * 16 + (l >> 4) * 4 + r;
            int byteoff = ((n * 16 + (l & 15)) * 2) ^ ((rowl & 7) << 4);
            Ps[rowl * 64 + (byteoff >> 1)] = f2bf(s[m][n][r]);
          }
      // O += P V
#pragma unroll
      for (int kg = 0; kg < 2; kg++) {
        bf16x8 pa[2], vb[4];
#pragma unroll
        for (int m = 0; m < 2; m++) {
          int rowl = w * 32 + m * 16 + (l & 15);
          int byteoff = ((kg * 32 + (l >> 4) * 8) * 2) ^ ((rowl & 7) << 4);
          pa[m] = ld16(Ps + rowl * 64 + (byteoff >> 1));
        }
#pragma unroll
        for (int n = 0; n < 4; n++) {
          int d = n * 16 + (l & 15);
          int byteoff = ((kg * 32 + (l >> 4) * 8) * 2) ^ ((d & 7) << 4);
          vb[n] = ld16(Vc + d * 64 + (byteoff >> 1));
        }
#pragma unroll
        for (int m = 0; m < 2; m++)
#pragma unroll
          for (int n = 0; n < 4; n++)
            o[m][n] = __builtin_amdgcn_mfma_f32_16x16x32_bf16(pa[m], vb[n], o[m][n], 0, 0, 0);
      }
    }

    asm volatile("s_waitcnt vmcnt(0)" ::: "memory");
    __builtin_amdgcn_s_barrier();
    cur ^= 1;
  }

  // write context [b][s][h*64+d]
#pragma unroll
  for (int m = 0; m < 2; m++)
#pragma unroll
    for (int r = 0; r < 4; r++) {
      float inv = 1.f / lrun[m][r];
      int qg = q0 + m * 16 + (l >> 4) * 4 + r;
#pragma unroll
      for (int n = 0; n < 4; n++) {
        int d = n * 16 + (l & 15);
        ctx[(size_t)(b * SEQ + qg) * DM + h * 64 + d] = f2bf(o[m][n][r] * inv);
      }
    }
}

extern "C" void kernel_launch(void* const* d_in, const int* in_sizes, int n_in,
                              void* d_out, int out_size, void* d_ws, size_t ws_size,
                              hipStream_t stream)
{
  const float* x     = (const float*)d_in[0];
  const float* qkv_w = (const float*)d_in[1];
  const float* qkv_b = (const float*)d_in[2];
  const float* out_w = (const float*)d_in[3];
  const float* out_b = (const float*)d_in[4];

  unsigned short* ws   = (unsigned short*)d_ws;
  unsigned short* xb   = ws;                          // 8192*1024
  unsigned short* wqT  = xb  + (size_t)8192 * 1024;   // 3072*1024
  unsigned short* woT  = wqT + 3072 * 1024;           // 1024*1024
  unsigned short* qkb  = woT + 1024 * 1024;           // 8192*2048 (Q|K)
  unsigned short* vTb  = qkb + (size_t)8192 * 2048;   // 128*64*1024 (V^T)
  unsigned short* ctxb = vTb + (size_t)128 * 64 * 1024; // 8192*1024  (~88 MB total)

  hipLaunchKernelGGL(cvt_f32_bf16, dim3(8192 * 1024 / 8 / 256), dim3(256), 0, stream,
                     x, xb, 8192 * 1024);
  hipLaunchKernelGGL(transpose_cvt, dim3(3072 / 32, 1024 / 32), dim3(32, 8), 0, stream,
                     qkv_w, wqT, 1024, 3072);
  hipLaunchKernelGGL(transpose_cvt, dim3(1024 / 32, 1024 / 32), dim3(32, 8), 0, stream,
                     out_w, woT, 1024, 1024);
  hipLaunchKernelGGL(gemm_bt<1>, dim3(64 * 24), dim3(256), 0, stream,
                     xb, wqT, qkv_b, (void*)qkb, vTb, 8192, 3072, 1024);
  hipLaunchKernelGGL(attn, dim3(8, 128), dim3(256), 0, stream,
                     qkb, vTb, ctxb);
  hipLaunchKernelGGL(gemm_bt<2>, dim3(64 * 8), dim3(256), 0, stream,
                     ctxb, woT, out_b, d_out, nullptr, 8192, 1024, 1024);
}